// Round 5
// baseline (324.501 us; speedup 1.0000x reference)
//
#include <hip/hip_runtime.h>

typedef _Float16 f16;
typedef _Float16 f16x8 __attribute__((ext_vector_type(8)));
typedef _Float16 f16x4 __attribute__((ext_vector_type(4)));
typedef float    f32x4 __attribute__((ext_vector_type(4)));

#define H_DIM 1024
#define S_DIM 1024
#define PLANE (1024*1024)
#define MT 128
#define NT 64
#define KT 32

// global -> LDS direct DMA, 16 B/lane; LDS dest = wave-uniform base + lane*16
__device__ __forceinline__ void load_lds16(const f16* g, f16* l) {
    __builtin_amdgcn_global_load_lds(
        (const __attribute__((address_space(1))) void*)g,
        (__attribute__((address_space(3))) void*)l, 16, 0, 0);
}

// Weight folding: Wa=W1+W3, Wb=W2-W3, Wc=W4 -> fp16 planes (12 MB in ws).
// prep_x is GONE: span_gemm v2 gathers x as f32 directly (in-reg cvt).
__global__ __launch_bounds__(256) void prep_w(
    const float* __restrict__ Wp1, const float* __restrict__ Wp2,
    const float* __restrict__ Wp3, const float* __restrict__ Wp4,
    const float* __restrict__ Wh1, const float* __restrict__ Wh2,
    const float* __restrict__ Wh3, const float* __restrict__ Wh4,
    f16* __restrict__ ws)
{
    const int tid  = blockIdx.x * 256 + threadIdx.x;   // < 524288
    const int span = tid >> 18;                        // 262144 chunks per span
    const size_t i = (size_t)(tid & 262143) * 4;
    const float* W1 = span ? Wh1 : Wp1;
    const float* W2 = span ? Wh2 : Wp2;
    const float* W3 = span ? Wh3 : Wp3;
    const float* W4 = span ? Wh4 : Wp4;
    f16* base = ws + (size_t)span * 3 * PLANE;

    f32x4 w1 = *(const f32x4*)(W1 + i);
    f32x4 w2 = *(const f32x4*)(W2 + i);
    f32x4 w3 = *(const f32x4*)(W3 + i);
    f32x4 w4 = *(const f32x4*)(W4 + i);

    f16x4 wa, wb, wc;
#pragma unroll
    for (int j = 0; j < 4; ++j) {
        wa[j] = (f16)(w1[j] + w3[j]);
        wb[j] = (f16)(w2[j] - w3[j]);
        wc[j] = (f16)w4[j];
    }
    *(f16x4*)(base + 0*PLANE + i) = wa;
    *(f16x4*)(base + 1*PLANE + i) = wb;
    *(f16x4*)(base + 2*PLANE + i) = wc;
}

// ---- span_gemm v2 ----
// A (gathered x rows) comes straight from f32 x via per-lane global loads into
// registers (distance-1 double-buffered reg sets, in-reg f16 RTN cvt == old
// prep_x rounding). Waves partition M (wm = wid*32) -> A is dup-free; each
// wave covers the full N=64 (nf 0..3).
// B (folded f16 weights) is DMA-staged into a 2x12 KB LDS double buffer.
// One barrier per step; all loads for step k+1 issue at top of step k;
// vmcnt(0)+barrier at step end (everything distance-1, always in flight
// during the MFMA clump). LDS-read/step/wave: 12 b128 (was 14), A off-LDS.
//
// B chunk swizzle kept from R4 (conflicts 0): LDS slot (row,c) holds global
// chunk c ^ ((row>>1)&3); read uses lqs = lq ^ ((lrow>>1)&3).
#define STEP(CURBUF, CUR, NXT, LAST)                                           \
  {                                                                            \
    if (!(LAST)) {                                                             \
      _Pragma("unroll")                                                        \
      for (int pl = 0; pl < 2; ++pl)                                           \
        _Pragma("unroll")                                                      \
        for (int mf = 0; mf < 2; ++mf) {                                       \
          const float* s = ab[pl][mf] + KT;                                    \
          NXT[pl][mf][0] = *(const f32x4*)(s);                                 \
          NXT[pl][mf][1] = *(const f32x4*)(s + 4);                             \
        }                                                                      \
      _Pragma("unroll")                                                        \
      for (int j = 0; j < 3; ++j)                                              \
        load_lds16(bq[j] + KT, &B_all[1 - (CURBUF)][bdst[j]]);                 \
    }                                                                          \
    f16x8 bf[3][4];                                                            \
    _Pragma("unroll")                                                          \
    for (int p = 0; p < 3; ++p)                                                \
      _Pragma("unroll")                                                        \
      for (int nf = 0; nf < 4; ++nf)                                           \
        bf[p][nf] = *(const f16x8*)&B_all[CURBUF][p * 2048 +                   \
                        (nf * 16 + lrow) * KT + lqs * 8];                      \
    f16x8 af[2][2];                                                            \
    _Pragma("unroll")                                                          \
    for (int pl = 0; pl < 2; ++pl)                                             \
      _Pragma("unroll")                                                        \
      for (int mf = 0; mf < 2; ++mf)                                           \
        _Pragma("unroll")                                                      \
        for (int e = 0; e < 4; ++e) {                                          \
          af[pl][mf][e]     = (f16)CUR[pl][mf][0][e];                          \
          af[pl][mf][4 + e] = (f16)CUR[pl][mf][1][e];                          \
        }                                                                      \
    _Pragma("unroll")                                                          \
    for (int mf = 0; mf < 2; ++mf)                                             \
      _Pragma("unroll")                                                        \
      for (int nf = 0; nf < 4; ++nf) {                                         \
        accL[mf][nf] = __builtin_amdgcn_mfma_f32_16x16x32_f16(af[0][mf], bf[0][nf], accL[mf][nf], 0,0,0); \
        accL[mf][nf] = __builtin_amdgcn_mfma_f32_16x16x32_f16(af[1][mf], bf[1][nf], accL[mf][nf], 0,0,0); \
        accP[mf][nf] = __builtin_amdgcn_mfma_f32_16x16x32_f16(af[0][mf], bf[2][nf], accP[mf][nf], 0,0,0); \
        accQ[mf][nf] = __builtin_amdgcn_mfma_f32_16x16x32_f16(af[1][mf], bf[2][nf], accQ[mf][nf], 0,0,0); \
      }                                                                        \
    if (!(LAST)) {                                                             \
      __asm__ volatile("s_waitcnt vmcnt(0)" ::: "memory");                     \
      __builtin_amdgcn_s_barrier();                                            \
      _Pragma("unroll")                                                        \
      for (int pl = 0; pl < 2; ++pl)                                           \
        _Pragma("unroll")                                                      \
        for (int mf = 0; mf < 2; ++mf) ab[pl][mf] += KT;                       \
      _Pragma("unroll")                                                        \
      for (int j = 0; j < 3; ++j) bq[j] += KT;                                 \
    }                                                                          \
  }

__global__ __launch_bounds__(256, 2) void span_gemm(
    const float* __restrict__ x,
    const int* __restrict__ idxP, const int* __restrict__ idxH,
    const f16* __restrict__ wpl,
    const float* __restrict__ bp1, const float* __restrict__ bp2, const float* __restrict__ bp4,
    const float* __restrict__ bh1, const float* __restrict__ bh2, const float* __restrict__ bh4,
    float* __restrict__ out)
{
    const int t     = threadIdx.x;
    const int mtile = blockIdx.x;
    const int ntile = blockIdx.y;
    const int span  = blockIdx.z;

    const int* idx   = span ? idxH : idxP;
    const f16* wbase = wpl + (size_t)span * 3 * PLANE;
    const float* b1 = span ? bh1 : bp1;
    const float* b2 = span ? bh2 : bp2;
    const float* b4 = span ? bh4 : bp4;
    float* obase = out + (size_t)span * 4096 * H_DIM;

    __shared__ __align__(16) f16 B_all[2][3 * NT * KT];   // 2 x 12 KB

    const int wid  = t >> 6;
    const int lane = t & 63;
    const int lrow = lane & 15;
    const int lq   = lane >> 4;
    const int lqs  = lq ^ ((lrow >> 1) & 3);           // swizzled read chunk
    const int schunk = (lane & 3) ^ ((lane >> 3) & 3); // DMA source chunk swz

    // A gather bases: 4 per lane ([plane=start/end][mf]), 64-bit, advance +KT/step
    const float* ab[2][2];
#pragma unroll
    for (int pl = 0; pl < 2; ++pl)
#pragma unroll
        for (int mf = 0; mf < 2; ++mf) {
            int rl = wid * 32 + mf * 16 + lrow;        // row_local in [0,128)
            int m  = mtile * MT + rl;
            int b  = m >> 8, kk = m & 255;
            int iv = idx[b * 512 + pl * 256 + kk];
            ab[pl][mf] = x + (size_t)(b * S_DIM + iv) * H_DIM + lq * 8;
        }

    // B DMA tasks: 3 ops/wave (12 total: 3 planes x 4 row-groups of 16)
    const f16* bq[3]; int bdst[3];
#pragma unroll
    for (int j = 0; j < 3; ++j) {
        int o = wid * 3 + j;
        int p = o >> 2, g = o & 3;
        int grow = ntile * NT + g * 16 + (lane >> 2);
        bq[j]   = wbase + (size_t)p * PLANE + (size_t)grow * H_DIM + schunk * 8;
        bdst[j] = p * 2048 + g * 16 * KT;
    }

    f32x4 accL[2][4], accP[2][4], accQ[2][4];
    {
        f32x4 z = {0.f, 0.f, 0.f, 0.f};
#pragma unroll
        for (int mf = 0; mf < 2; ++mf)
#pragma unroll
            for (int nf = 0; nf < 4; ++nf) { accL[mf][nf] = z; accP[mf][nf] = z; accQ[mf][nf] = z; }
    }

    // prologue: A(0) -> reg set 0, B(0) -> buf0; drain; barrier
    f32x4 a32_0[2][2][2], a32_1[2][2][2];
#pragma unroll
    for (int pl = 0; pl < 2; ++pl)
#pragma unroll
        for (int mf = 0; mf < 2; ++mf) {
            a32_0[pl][mf][0] = *(const f32x4*)(ab[pl][mf]);
            a32_0[pl][mf][1] = *(const f32x4*)(ab[pl][mf] + 4);
        }
#pragma unroll
    for (int j = 0; j < 3; ++j) load_lds16(bq[j], &B_all[0][bdst[j]]);
    __asm__ volatile("s_waitcnt vmcnt(0)" ::: "memory");
    __builtin_amdgcn_s_barrier();

    // 32 k-steps = 16 double-steps; buffer/reg parity is compile-time
#pragma unroll
    for (int tt = 0; tt < 16; ++tt) {
        STEP(0, a32_0, a32_1, 0);
        STEP(1, a32_1, a32_0, (tt == 15));
    }

    // epilogue: span = L + b1 + b2 + (P+b4)*(Q+b4); out = tanh(span)
    // C/D layout (m89-verified): col = lane&15, row = (lane>>4)*4 + i
#pragma unroll
    for (int mf = 0; mf < 2; ++mf)
#pragma unroll
        for (int nf = 0; nf < 4; ++nf) {
            int col = ntile * NT + nf * 16 + lrow;
            float bb12 = b1[col] + b2[col];
            float bb4  = b4[col];
            int row0 = mtile * MT + wid * 32 + mf * 16 + lq * 4;
#pragma unroll
            for (int i = 0; i < 4; ++i) {
                float v = accL[mf][nf][i] + bb12
                        + (accP[mf][nf][i] + bb4) * (accQ[mf][nf][i] + bb4);
                obase[(size_t)(row0 + i) * H_DIM + col] = tanhf(v);
            }
        }
}

extern "C" void kernel_launch(void* const* d_in, const int* in_sizes, int n_in,
                              void* d_out, int out_size, void* d_ws, size_t ws_size,
                              hipStream_t stream) {
    (void)in_sizes; (void)n_in; (void)out_size; (void)ws_size;
    const float* x    = (const float*)d_in[0];
    const int*   idxP = (const int*)d_in[1];
    const int*   idxH = (const int*)d_in[2];
    const float* Wp1 = (const float*)d_in[3];  const float* bp1 = (const float*)d_in[4];
    const float* Wp2 = (const float*)d_in[5];  const float* bp2 = (const float*)d_in[6];
    const float* Wp3 = (const float*)d_in[7];
    const float* Wp4 = (const float*)d_in[9];  const float* bp4 = (const float*)d_in[10];
    const float* Wh1 = (const float*)d_in[11]; const float* bh1 = (const float*)d_in[12];
    const float* Wh2 = (const float*)d_in[13]; const float* bh2 = (const float*)d_in[14];
    const float* Wh3 = (const float*)d_in[15];
    const float* Wh4 = (const float*)d_in[17]; const float* bh4 = (const float*)d_in[18];
    float* out = (float*)d_out;
    f16*   ws  = (f16*)d_ws;   // folded weights only: 12 MB

    prep_w<<<2048, 256, 0, stream>>>(Wp1, Wp2, Wp3, Wp4,
                                     Wh1, Wh2, Wh3, Wh4, ws);
    span_gemm<<<dim3(32, 16, 2), 256, 0, stream>>>(x, idxP, idxH, ws,
                                                   bp1, bp2, bp4, bh1, bh2, bh4, out);
}

// Round 7
// 300.387 us; speedup vs baseline: 1.0803x; 1.0803x over previous
//
#include <hip/hip_runtime.h>

typedef _Float16 f16;
typedef _Float16 f16x8 __attribute__((ext_vector_type(8)));
typedef _Float16 f16x4 __attribute__((ext_vector_type(4)));
typedef float    f32x4 __attribute__((ext_vector_type(4)));

#define H_DIM 1024
#define S_DIM 1024
#define PLANE (1024*1024)
#define MT 128
#define NT 64
#define KT 32

// global -> LDS direct DMA, 16 B/lane; LDS dest = wave-uniform base + lane*16
__device__ __forceinline__ void load_lds16(const f16* g, f16* l) {
    __builtin_amdgcn_global_load_lds(
        (const __attribute__((address_space(1))) void*)g,
        (__attribute__((address_space(3))) void*)l, 16, 0, 0);
}

// Weight folding: Wa=W1+W3, Wb=W2-W3, Wc=W4 -> fp16 planes (12 MB in ws).
__global__ __launch_bounds__(256) void prep_w(
    const float* __restrict__ Wp1, const float* __restrict__ Wp2,
    const float* __restrict__ Wp3, const float* __restrict__ Wp4,
    const float* __restrict__ Wh1, const float* __restrict__ Wh2,
    const float* __restrict__ Wh3, const float* __restrict__ Wh4,
    f16* __restrict__ ws)
{
    const int tid  = blockIdx.x * 256 + threadIdx.x;   // < 524288
    const int span = tid >> 18;                        // 262144 chunks per span
    const size_t i = (size_t)(tid & 262143) * 4;
    const float* W1 = span ? Wh1 : Wp1;
    const float* W2 = span ? Wh2 : Wp2;
    const float* W3 = span ? Wh3 : Wp3;
    const float* W4 = span ? Wh4 : Wp4;
    f16* base = ws + (size_t)span * 3 * PLANE;

    f32x4 w1 = *(const f32x4*)(W1 + i);
    f32x4 w2 = *(const f32x4*)(W2 + i);
    f32x4 w3 = *(const f32x4*)(W3 + i);
    f32x4 w4 = *(const f32x4*)(W4 + i);

    f16x4 wa, wb, wc;
#pragma unroll
    for (int j = 0; j < 4; ++j) {
        wa[j] = (f16)(w1[j] + w3[j]);
        wb[j] = (f16)(w2[j] - w3[j]);
        wc[j] = (f16)w4[j];
    }
    *(f16x4*)(base + 0*PLANE + i) = wa;
    *(f16x4*)(base + 1*PLANE + i) = wb;
    *(f16x4*)(base + 2*PLANE + i) = wc;
}

// ---- span_gemm v4: distance-2 EVERYWHERE, order-robust vmcnt ----
// R6 failed because its vmcnt(8) assumed the compiler preserved the
// [B-DMA x3, A-load x8] issue order (no-alias -> it may reorder; half-written
// B tiles were consumed). v4 invariant needs NO intra-step order:
//   outstanding at step entry <= 11 (only step k-1's issues)
//   step k issues <= 11 (3 B-DMA + 8 A-loads, any interleave)
//   end-of-step s_waitcnt vmcnt(11) => ALL step-(k-1)-or-older ops landed
//   => B(k+1) [LDS buf (k+1)%3] and A(k+1) [reg set (k+1)&1] ready.
// B: 3 rotating LDS bufs (36 KB total), DMA'd at distance 2.
// A: per-lane f32 global loads (gather), 2 reg sets by parity, distance 2,
//    in-reg f16 RTN cvt (== old prep_x rounding; R5 passed with this layout).
// Prologue: issue B0,A0,B1,A1 then one vmcnt(0) drain (order-free).
// XCD remap: 16 blocks sharing one (mtile,span) A-row-set (512 KB) land on
// one XCD -> the 16x A-gather duplication is L2-served, not L3.
#define STEP(P, RB, WB, ISS)                                                   \
  {                                                                            \
    f16x8 af[2][2];                                                            \
    _Pragma("unroll")                                                          \
    for (int pl = 0; pl < 2; ++pl)                                             \
      _Pragma("unroll")                                                        \
      for (int mf = 0; mf < 2; ++mf)                                           \
        _Pragma("unroll")                                                      \
        for (int e = 0; e < 4; ++e) {                                          \
          af[pl][mf][e]     = (f16)aw##P[pl][mf][0][e];                        \
          af[pl][mf][4 + e] = (f16)aw##P[pl][mf][1][e];                        \
        }                                                                      \
    if (ISS) {                                                                 \
      _Pragma("unroll")                                                        \
      for (int j = 0; j < 3; ++j) { load_lds16(bq[j], &B_all[WB][bdst[j]]); bq[j] += KT; } \
      _Pragma("unroll")                                                        \
      for (int pl = 0; pl < 2; ++pl)                                           \
        _Pragma("unroll")                                                      \
        for (int mf = 0; mf < 2; ++mf) {                                       \
          aw##P[pl][mf][0] = *(const f32x4*)(ab[pl][mf]);                      \
          aw##P[pl][mf][1] = *(const f32x4*)(ab[pl][mf] + 4);                  \
          ab[pl][mf] += KT;                                                    \
        }                                                                      \
    }                                                                          \
    f16x8 bf[3][4];                                                            \
    _Pragma("unroll")                                                          \
    for (int p = 0; p < 3; ++p)                                                \
      _Pragma("unroll")                                                        \
      for (int nf = 0; nf < 4; ++nf)                                           \
        bf[p][nf] = *(const f16x8*)&B_all[RB][p * 2048 + (nf * 16 + lrow) * KT + lqs * 8]; \
    _Pragma("unroll")                                                          \
    for (int mf = 0; mf < 2; ++mf)                                             \
      _Pragma("unroll")                                                        \
      for (int nf = 0; nf < 4; ++nf) {                                         \
        accL[mf][nf] = __builtin_amdgcn_mfma_f32_16x16x32_f16(af[0][mf], bf[0][nf], accL[mf][nf], 0,0,0); \
        accL[mf][nf] = __builtin_amdgcn_mfma_f32_16x16x32_f16(af[1][mf], bf[1][nf], accL[mf][nf], 0,0,0); \
        accP[mf][nf] = __builtin_amdgcn_mfma_f32_16x16x32_f16(af[0][mf], bf[2][nf], accP[mf][nf], 0,0,0); \
        accQ[mf][nf] = __builtin_amdgcn_mfma_f32_16x16x32_f16(af[1][mf], bf[2][nf], accQ[mf][nf], 0,0,0); \
      }                                                                        \
    if (ISS) { __asm__ volatile("s_waitcnt vmcnt(11)" ::: "memory"); }         \
    else     { __asm__ volatile("s_waitcnt vmcnt(0)"  ::: "memory"); }         \
    __builtin_amdgcn_s_barrier();                                              \
  }

// Final step: compute only, no sync/issue.
#define STEP_FIN(P, RB)                                                        \
  {                                                                            \
    f16x8 af[2][2];                                                            \
    _Pragma("unroll")                                                          \
    for (int pl = 0; pl < 2; ++pl)                                             \
      _Pragma("unroll")                                                        \
      for (int mf = 0; mf < 2; ++mf)                                           \
        _Pragma("unroll")                                                      \
        for (int e = 0; e < 4; ++e) {                                          \
          af[pl][mf][e]     = (f16)aw##P[pl][mf][0][e];                        \
          af[pl][mf][4 + e] = (f16)aw##P[pl][mf][1][e];                        \
        }                                                                      \
    f16x8 bf[3][4];                                                            \
    _Pragma("unroll")                                                          \
    for (int p = 0; p < 3; ++p)                                                \
      _Pragma("unroll")                                                        \
      for (int nf = 0; nf < 4; ++nf)                                           \
        bf[p][nf] = *(const f16x8*)&B_all[RB][p * 2048 + (nf * 16 + lrow) * KT + lqs * 8]; \
    _Pragma("unroll")                                                          \
    for (int mf = 0; mf < 2; ++mf)                                             \
      _Pragma("unroll")                                                        \
      for (int nf = 0; nf < 4; ++nf) {                                         \
        accL[mf][nf] = __builtin_amdgcn_mfma_f32_16x16x32_f16(af[0][mf], bf[0][nf], accL[mf][nf], 0,0,0); \
        accL[mf][nf] = __builtin_amdgcn_mfma_f32_16x16x32_f16(af[1][mf], bf[1][nf], accL[mf][nf], 0,0,0); \
        accP[mf][nf] = __builtin_amdgcn_mfma_f32_16x16x32_f16(af[0][mf], bf[2][nf], accP[mf][nf], 0,0,0); \
        accQ[mf][nf] = __builtin_amdgcn_mfma_f32_16x16x32_f16(af[1][mf], bf[2][nf], accQ[mf][nf], 0,0,0); \
      }                                                                        \
  }

__global__ __launch_bounds__(256, 2) void span_gemm(
    const float* __restrict__ x,
    const int* __restrict__ idxP, const int* __restrict__ idxH,
    const f16* __restrict__ wpl,
    const float* __restrict__ bp1, const float* __restrict__ bp2, const float* __restrict__ bp4,
    const float* __restrict__ bh1, const float* __restrict__ bh2, const float* __restrict__ bh4,
    float* __restrict__ out)
{
    const int t = threadIdx.x;

    // XCD-aware decode of linear block id (grid = 1024 x 1 x 1).
    // xcd = L&7; group g = gq*8+xcd encodes (mtile,span); ntile cycles within.
    // All 16 ntile-blocks of one (mtile,span) share 128 A-rows (512 KB) on
    // one XCD's L2. Bijective on [0,1024).
    const int L     = blockIdx.x;
    const int xcd   = L & 7;
    const int r     = L >> 3;
    const int ntile = r & 15;
    const int g     = (r >> 4) * 8 + xcd;
    const int mtile = g & 31;
    const int span  = g >> 5;

    const int* idx   = span ? idxH : idxP;
    const f16* wbase = wpl + (size_t)span * 3 * PLANE;
    const float* b1 = span ? bh1 : bp1;
    const float* b2 = span ? bh2 : bp2;
    const float* b4 = span ? bh4 : bp4;
    float* obase = out + (size_t)span * 4096 * H_DIM;

    __shared__ __align__(16) f16 B_all[3][3 * NT * KT];   // 3 x 12 KB = 36 KB

    const int wid  = t >> 6;
    const int lane = t & 63;
    const int lrow = lane & 15;
    const int lq   = lane >> 4;
    const int lqs  = lq ^ ((lrow >> 1) & 3);           // swizzled read chunk
    const int schunk = (lane & 3) ^ ((lane >> 3) & 3); // DMA source chunk swz

    // A gather bases: 4 per lane ([plane=start/end][mf]); advance +KT/step
    const float* ab[2][2];
#pragma unroll
    for (int pl = 0; pl < 2; ++pl)
#pragma unroll
        for (int mf = 0; mf < 2; ++mf) {
            int rl = wid * 32 + mf * 16 + lrow;        // row_local in [0,128)
            int m  = mtile * MT + rl;
            int b  = m >> 8, kk = m & 255;
            int iv = idx[b * 512 + pl * 256 + kk];
            ab[pl][mf] = x + (size_t)(b * S_DIM + iv) * H_DIM + lq * 8;
        }

    // B DMA tasks: 3 ops/wave (12 total: 3 planes x 4 row-groups of 16)
    const f16* bq[3]; int bdst[3];
#pragma unroll
    for (int j = 0; j < 3; ++j) {
        int o = wid * 3 + j;
        int p = o >> 2, gg = o & 3;
        int grow = ntile * NT + gg * 16 + (lane >> 2);
        bq[j]   = wbase + (size_t)p * PLANE + (size_t)grow * H_DIM + schunk * 8;
        bdst[j] = p * 2048 + gg * 16 * KT;
    }

    f32x4 accL[2][4], accP[2][4], accQ[2][4];
    {
        f32x4 z = {0.f, 0.f, 0.f, 0.f};
#pragma unroll
        for (int mf = 0; mf < 2; ++mf)
#pragma unroll
            for (int nf = 0; nf < 4; ++nf) { accL[mf][nf] = z; accP[mf][nf] = z; accQ[mf][nf] = z; }
    }

    // prologue: B0->buf0, A0->set0, B1->buf1, A1->set1; ONE full drain.
    // (Order-free: vmcnt(0) is correct under any interleaving.)
    f32x4 aw0[2][2][2], aw1[2][2][2];
#pragma unroll
    for (int j = 0; j < 3; ++j) { load_lds16(bq[j], &B_all[0][bdst[j]]); bq[j] += KT; }
#pragma unroll
    for (int j = 0; j < 3; ++j) { load_lds16(bq[j], &B_all[1][bdst[j]]); bq[j] += KT; }
#pragma unroll
    for (int pl = 0; pl < 2; ++pl)
#pragma unroll
        for (int mf = 0; mf < 2; ++mf) {
            aw0[pl][mf][0] = *(const f32x4*)(ab[pl][mf]);
            aw0[pl][mf][1] = *(const f32x4*)(ab[pl][mf] + 4);
            aw1[pl][mf][0] = *(const f32x4*)(ab[pl][mf] + KT);
            aw1[pl][mf][1] = *(const f32x4*)(ab[pl][mf] + KT + 4);
            ab[pl][mf] += 2 * KT;
        }
    __asm__ volatile("s_waitcnt vmcnt(0)" ::: "memory");
    __builtin_amdgcn_s_barrier();

    // k = 0..29: period-6 pattern (P = k&1, RB = k%3, WB = (k+2)%3), x5
#pragma unroll
    for (int tt = 0; tt < 5; ++tt) {
        STEP(0, 0, 2, 1);
        STEP(1, 1, 0, 1);
        STEP(0, 2, 1, 1);
        STEP(1, 0, 2, 1);
        STEP(0, 1, 0, 1);
        STEP(1, 2, 1, 1);
    }
    STEP(0, 0, 0, 0);    // k=30: no issues, vmcnt(0) drains B31+A31
    STEP_FIN(1, 1);      // k=31: compute only

    // epilogue: span = L + b1 + b2 + (P+b4)*(Q+b4); out = tanh(span)
    // C/D layout (m89-verified): col = lane&15, row = (lane>>4)*4 + i
#pragma unroll
    for (int mf = 0; mf < 2; ++mf)
#pragma unroll
        for (int nf = 0; nf < 4; ++nf) {
            int col = ntile * NT + nf * 16 + lrow;
            float bb12 = b1[col] + b2[col];
            float bb4  = b4[col];
            int row0 = mtile * MT + wid * 32 + mf * 16 + lq * 4;
#pragma unroll
            for (int i = 0; i < 4; ++i) {
                float v = accL[mf][nf][i] + bb12
                        + (accP[mf][nf][i] + bb4) * (accQ[mf][nf][i] + bb4);
                obase[(size_t)(row0 + i) * H_DIM + col] = tanhf(v);
            }
        }
}

extern "C" void kernel_launch(void* const* d_in, const int* in_sizes, int n_in,
                              void* d_out, int out_size, void* d_ws, size_t ws_size,
                              hipStream_t stream) {
    (void)in_sizes; (void)n_in; (void)out_size; (void)ws_size;
    const float* x    = (const float*)d_in[0];
    const int*   idxP = (const int*)d_in[1];
    const int*   idxH = (const int*)d_in[2];
    const float* Wp1 = (const float*)d_in[3];  const float* bp1 = (const float*)d_in[4];
    const float* Wp2 = (const float*)d_in[5];  const float* bp2 = (const float*)d_in[6];
    const float* Wp3 = (const float*)d_in[7];
    const float* Wp4 = (const float*)d_in[9];  const float* bp4 = (const float*)d_in[10];
    const float* Wh1 = (const float*)d_in[11]; const float* bh1 = (const float*)d_in[12];
    const float* Wh2 = (const float*)d_in[13]; const float* bh2 = (const float*)d_in[14];
    const float* Wh3 = (const float*)d_in[15];
    const float* Wh4 = (const float*)d_in[17]; const float* bh4 = (const float*)d_in[18];
    float* out = (float*)d_out;
    f16*   ws  = (f16*)d_ws;   // folded weights only: 12 MB

    prep_w<<<2048, 256, 0, stream>>>(Wp1, Wp2, Wp3, Wp4,
                                     Wh1, Wh2, Wh3, Wh4, ws);
    span_gemm<<<1024, 256, 0, stream>>>(x, idxP, idxH, ws,
                                        bp1, bp2, bp4, bh1, bh2, bh4, out);
}

// Round 8
// 247.576 us; speedup vs baseline: 1.3107x; 1.2133x over previous
//
#include <hip/hip_runtime.h>
#include <hip/hip_bf16.h>

typedef _Float16 f16;
typedef _Float16 f16x4 __attribute__((ext_vector_type(4)));
typedef _Float16 f16x8 __attribute__((ext_vector_type(8)));
typedef float    f32x4 __attribute__((ext_vector_type(4)));

#define H_DIM 1024
#define S_DIM 1024
#define PLANE (1024*1024)
#define MT 128
#define NT 64
#define KT 32
#define AP (MT*KT)        // one A plane in LDS, f16 elems (4096)
#define ABUF (2*AP)       // one A buffer (2 planes), 8192 f16 = 16 KB
#define XOFF (6*PLANE)    // x_f16 after 2 spans * 3 weight planes

// global -> LDS direct DMA, 16 B/lane; LDS dest = wave-uniform base + lane*16
__device__ __forceinline__ void load_lds16(const f16* g, f16* l) {
    __builtin_amdgcn_global_load_lds(
        (const __attribute__((address_space(1))) void*)g,
        (__attribute__((address_space(3))) void*)l, 16, 0, 0);
}

// Merged prep, ILP-heavy grid-stride form (2560 blocks = 10/CU, one residency
// round, no launch churn):
//   blocks [0,2048):   x fp32->fp16. 8 block-local consecutive chunks/thread
//                      (128 B/thread, 8 independent loads in flight).
//   blocks [2048,2560): weight fold Wa=W1+W3, Wb=W2-W3, Wc=W4 -> f16 planes.
//                      4 chunks/thread x 4 planes = 16 loads in flight.
// R5/R7 lesson does NOT apply here (no pipeline to poison — pure streaming).
__global__ __launch_bounds__(256) void prep_all(
    const float* __restrict__ x,
    const float* __restrict__ Wp1, const float* __restrict__ Wp2,
    const float* __restrict__ Wp3, const float* __restrict__ Wp4,
    const float* __restrict__ Wh1, const float* __restrict__ Wh2,
    const float* __restrict__ Wh3, const float* __restrict__ Wh4,
    f16* __restrict__ ws)
{
    const int t  = threadIdx.x;
    const int bx = blockIdx.x;
    if (bx < 2048) {
        // 2048 blocks x 2048 chunks = 4,194,304 f32x4 chunks = 16.78M floats
        const size_t b0 = (size_t)bx * 2048;
#pragma unroll
        for (int it = 0; it < 8; ++it) {
            const size_t i = (b0 + it * 256 + t) * 4;
            f32x4 v = *(const f32x4*)(x + i);
            f16x4 h;
#pragma unroll
            for (int j = 0; j < 4; ++j) h[j] = (f16)v[j];
            *(f16x4*)(ws + XOFF + i) = h;
        }
        return;
    }
    // 512 blocks x 1024 chunks = 524,288 chunks = 2 spans x 1M floats
    const int wb = bx - 2048;
#pragma unroll
    for (int it = 0; it < 4; ++it) {
        const int c    = wb * 1024 + it * 256 + t;     // < 524288
        const int span = c >> 18;
        const size_t i = (size_t)(c & 262143) * 4;
        const float* W1 = span ? Wh1 : Wp1;
        const float* W2 = span ? Wh2 : Wp2;
        const float* W3 = span ? Wh3 : Wp3;
        const float* W4 = span ? Wh4 : Wp4;
        f16* base = ws + (size_t)span * 3 * PLANE;

        f32x4 w1 = *(const f32x4*)(W1 + i);
        f32x4 w2 = *(const f32x4*)(W2 + i);
        f32x4 w3 = *(const f32x4*)(W3 + i);
        f32x4 w4 = *(const f32x4*)(W4 + i);

        f16x4 wa, wb2, wc;
#pragma unroll
        for (int j = 0; j < 4; ++j) {
            wa[j]  = (f16)(w1[j] + w3[j]);
            wb2[j] = (f16)(w2[j] - w3[j]);
            wc[j]  = (f16)w4[j];
        }
        *(f16x4*)(base + 0*PLANE + i) = wa;
        *(f16x4*)(base + 1*PLANE + i) = wb2;
        *(f16x4*)(base + 2*PLANE + i) = wc;
    }
}

// One pipeline step (R4-VERIFIED STRUCTURE — all-DMA, no register-dest global
// loads in the loop; the compiler has no vmcnt deps to conservatively
// re-wait on, which killed R5/R7's register-gather variants).
//   FB: DMA B(k+1) into the (single) B buffer; FA: DMA A(k+2) into A buf wbA.
//   WCNT: vmcnt kept in flight at the step-end wait (4 = A(k+2); 0 at tail).
//   FIN: final step — no barriers/DMA.
// Two-barrier step: frag reads -> lgkmcnt(0)+bar1 (reads retired, B buf safe
// to overwrite) -> DMA issues (untracked, vmcnt only) -> MFMAs -> vmcnt(WCNT)
// +bar2 (next kstep's data landed; fresh A(k+2) prefetch STAYS in flight).
//
// LDS swizzle (T2 via rule 21, R4-verified: SQ_LDS_BANK_CONFLICT 7.34M -> 0):
//   LDS slot (row, c) holds global chunk c ^ ((row>>1)&3) of that row.
//   Read of global chunk lq: address chunk lqs = lq ^ ((lrow>>1)&3).
#define K_STEP(FB, FA, WCNT, FIN)                                              \
  {                                                                            \
    f16x8 afr0[4], afr1[4], bfrg[6];                                           \
    const f16* Ab = &A_all[rbA];                                               \
    _Pragma("unroll")                                                          \
    for (int mf = 0; mf < 4; ++mf) {                                           \
      int r = (wm + mf * 16 + lrow) * KT + lqs * 8;                            \
      afr0[mf] = *(const f16x8*)&Ab[r];                                        \
      afr1[mf] = *(const f16x8*)&Ab[AP + r];                                   \
    }                                                                          \
    _Pragma("unroll")                                                          \
    for (int j = 0; j < 6; ++j) {                                              \
      int p = j >> 1, nf = j & 1;                                              \
      bfrg[j] = *(const f16x8*)&B_lds[p * 2048 + (wn + nf * 16 + lrow) * KT + lqs * 8]; \
    }                                                                          \
    if (!(FIN)) {                                                              \
      __asm__ volatile("s_waitcnt lgkmcnt(0)" ::: "memory");                   \
      __builtin_amdgcn_s_barrier();                                            \
      if (FB) {                                                                \
        _Pragma("unroll")                                                      \
        for (int j = 0; j < 3; ++j) { load_lds16(bq[j], &B_lds[bdst[j]]); bq[j] += KT; } \
      }                                                                        \
      if (FA) {                                                                \
        f16* dst = &A_all[wbA];                                                \
        _Pragma("unroll")                                                      \
        for (int j = 0; j < 4; ++j) { load_lds16(ap[j], dst + adst[j]); ap[j] += KT; } \
      }                                                                        \
    }                                                                          \
    _Pragma("unroll")                                                          \
    for (int mf = 0; mf < 4; ++mf)                                             \
      _Pragma("unroll")                                                        \
      for (int nf = 0; nf < 2; ++nf) {                                         \
        accL[mf][nf] = __builtin_amdgcn_mfma_f32_16x16x32_f16(afr0[mf], bfrg[0*2+nf], accL[mf][nf], 0,0,0); \
        accL[mf][nf] = __builtin_amdgcn_mfma_f32_16x16x32_f16(afr1[mf], bfrg[1*2+nf], accL[mf][nf], 0,0,0); \
        accP[mf][nf] = __builtin_amdgcn_mfma_f32_16x16x32_f16(afr0[mf], bfrg[2*2+nf], accP[mf][nf], 0,0,0); \
        accQ[mf][nf] = __builtin_amdgcn_mfma_f32_16x16x32_f16(afr1[mf], bfrg[2*2+nf], accQ[mf][nf], 0,0,0); \
      }                                                                        \
    if (!(FIN)) {                                                              \
      __asm__ volatile("s_waitcnt vmcnt(" #WCNT ")" ::: "memory");             \
      __builtin_amdgcn_s_barrier();                                            \
      rbA = (rbA == 2 * ABUF) ? 0 : rbA + ABUF;                                \
      wbA = (wbA == 2 * ABUF) ? 0 : wbA + ABUF;                                \
    }                                                                          \
  }

// Fused gather + 4-plane fp16 GEMM + bias/product/tanh epilogue.
// A: LDS 3 bufs (48 KB), distance-2 DMA. B: LDS 1 buf (12 KB), in-place
// refresh guarded by barrier1. Total 60 KB < 64 KB cap -> 2 blocks/CU.
// Grid: (32 m-tiles, 16 n-tiles, 2 spans). Block: 256 (4 waves, 2x2 of 64x32).
__global__ __launch_bounds__(256) void span_gemm(
    const f16* __restrict__ xh,
    const int* __restrict__ idxP, const int* __restrict__ idxH,
    const f16* __restrict__ wpl,
    const float* __restrict__ bp1, const float* __restrict__ bp2, const float* __restrict__ bp4,
    const float* __restrict__ bh1, const float* __restrict__ bh2, const float* __restrict__ bh4,
    float* __restrict__ out)
{
    const int t     = threadIdx.x;
    const int mtile = blockIdx.x;
    const int ntile = blockIdx.y;
    const int span  = blockIdx.z;

    const int* idx   = span ? idxH : idxP;
    const f16* wbase = wpl + (size_t)span * 3 * PLANE;
    const float* b1 = span ? bh1 : bp1;
    const float* b2 = span ? bh2 : bp2;
    const float* b4 = span ? bh4 : bp4;
    float* obase = out + (size_t)span * 4096 * H_DIM;

    __shared__ __align__(16) f16 A_all[3 * ABUF];   // 48 KB
    __shared__ __align__(16) f16 B_lds[3 * NT * KT]; // 12 KB, single buffer

    // rowoff aliased onto A buf0 (consumed into registers before first DMA)
    int* rowoff = (int*)A_all;
    {
        int side = t >> 7, m = t & 127;
        int bk = mtile * MT + m;
        int b  = bk >> 8, kk = bk & 255;
        rowoff[side * 128 + m] = (b * S_DIM + idx[b * 512 + side * 256 + kk]) * H_DIM;
    }
    __syncthreads();

    const int wid  = t >> 6;
    const int lane = t & 63;
    const int wm   = (wid & 1) * 64;
    const int wn   = (wid >> 1) * 32;
    const int lrow = lane & 15;
    const int lq   = lane >> 4;
    const int lqs  = lq ^ ((lrow >> 1) & 3);   // swizzled read chunk

    // DMA source chunk swizzle: LDS slot chunk (lane&3) of row_local (lane>>2)
    // must hold global chunk (lane&3) ^ ((row_local>>1)&3).
    const int schunk = (lane & 3) ^ ((lane >> 3) & 3);

    // A DMA tasks: 4 ops/wave, each 16 rows x 64 B (contiguous 1 KB block)
    const f16* ap[4]; int adst[4];
#pragma unroll
    for (int j = 0; j < 4; ++j) {
        int o = wid * 4 + j;
        int p = o >> 3, g = o & 7;
        int r = g * 16 + (lane >> 2);
        ap[j]   = xh + rowoff[p * 128 + r] + schunk * 8;
        adst[j] = p * AP + g * 16 * KT;
    }
    __syncthreads();   // all rowoff reads done before DMA overwrites buf0

    // B DMA tasks: 3 ops/wave (12 total: 3 planes x 4 row-groups of 16)
    const f16* bq[3]; int bdst[3];
#pragma unroll
    for (int j = 0; j < 3; ++j) {
        int o = wid * 3 + j;
        int p = o >> 2, g = o & 3;
        int grow = ntile * NT + g * 16 + (lane >> 2);
        bq[j]   = wbase + (size_t)p * PLANE + (size_t)grow * H_DIM + schunk * 8;
        bdst[j] = p * 2048 + g * 16 * KT;
    }

    f32x4 accL[4][2], accP[4][2], accQ[4][2];
    {
        f32x4 z = {0.f, 0.f, 0.f, 0.f};
#pragma unroll
        for (int mf = 0; mf < 4; ++mf)
#pragma unroll
            for (int nf = 0; nf < 2; ++nf) { accL[mf][nf] = z; accP[mf][nf] = z; accQ[mf][nf] = z; }
    }

    // prologue: A(0), B(0), A(1); drain A(0)+B(0), keep A(1) in flight
#pragma unroll
    for (int j = 0; j < 4; ++j) { load_lds16(ap[j], &A_all[0 * ABUF + adst[j]]); ap[j] += KT; }
#pragma unroll
    for (int j = 0; j < 3; ++j) { load_lds16(bq[j], &B_lds[bdst[j]]); bq[j] += KT; }
#pragma unroll
    for (int j = 0; j < 4; ++j) { load_lds16(ap[j], &A_all[1 * ABUF + adst[j]]); ap[j] += KT; }
    __asm__ volatile("s_waitcnt vmcnt(4)" ::: "memory");
    __builtin_amdgcn_s_barrier();

    int rbA = 0;          // A read buffer (kstep k)
    int wbA = 2 * ABUF;   // A write buffer (kstep k+2)

    for (int ks = 0; ks < 30; ++ks) {
        K_STEP(1, 1, 4, 0);
    }
    K_STEP(1, 0, 0, 0);   // ks=30: fill B(31), no A(32), drain all
    K_STEP(0, 0, 0, 1);   // ks=31: compute only

    // epilogue: span = L + b1 + b2 + (P+b4)*(Q+b4); out = tanh(span)
    // C/D layout (m89-verified): col = lane&15, row = (lane>>4)*4 + i
#pragma unroll
    for (int mf = 0; mf < 4; ++mf)
#pragma unroll
        for (int nf = 0; nf < 2; ++nf) {
            int col = ntile * NT + wn + nf * 16 + lrow;
            float bb12 = b1[col] + b2[col];
            float bb4  = b4[col];
            int row0 = mtile * MT + wm + mf * 16 + lq * 4;
#pragma unroll
            for (int i = 0; i < 4; ++i) {
                float v = accL[mf][nf][i] + bb12
                        + (accP[mf][nf][i] + bb4) * (accQ[mf][nf][i] + bb4);
                obase[(size_t)(row0 + i) * H_DIM + col] = tanhf(v);
            }
        }
}

extern "C" void kernel_launch(void* const* d_in, const int* in_sizes, int n_in,
                              void* d_out, int out_size, void* d_ws, size_t ws_size,
                              hipStream_t stream) {
    (void)in_sizes; (void)n_in; (void)out_size; (void)ws_size;
    const float* x    = (const float*)d_in[0];
    const int*   idxP = (const int*)d_in[1];
    const int*   idxH = (const int*)d_in[2];
    const float* Wp1 = (const float*)d_in[3];  const float* bp1 = (const float*)d_in[4];
    const float* Wp2 = (const float*)d_in[5];  const float* bp2 = (const float*)d_in[6];
    const float* Wp3 = (const float*)d_in[7];
    const float* Wp4 = (const float*)d_in[9];  const float* bp4 = (const float*)d_in[10];
    const float* Wh1 = (const float*)d_in[11]; const float* bh1 = (const float*)d_in[12];
    const float* Wh2 = (const float*)d_in[13]; const float* bh2 = (const float*)d_in[14];
    const float* Wh3 = (const float*)d_in[15];
    const float* Wh4 = (const float*)d_in[17]; const float* bh4 = (const float*)d_in[18];
    float* out = (float*)d_out;
    f16*   ws  = (f16*)d_ws;   // weights 12 MB + x_f16 32 MB = 44 MB

    prep_all<<<2560, 256, 0, stream>>>(x, Wp1, Wp2, Wp3, Wp4,
                                       Wh1, Wh2, Wh3, Wh4, ws);
    span_gemm<<<dim3(32, 16, 2), 256, 0, stream>>>(ws + XOFF, idxP, idxH, ws,
                                                   bp1, bp2, bp4, bh1, bh2, bh4, out);
}